// Round 4
// baseline (348.086 us; speedup 1.0000x reference)
//
#include <hip/hip_runtime.h>

typedef unsigned int  uint32;
typedef unsigned short u16;

// ---------- bf16 pack/unpack (intermediate y only) ----------
__device__ __forceinline__ uint32 pk2(float a, float b){
  union {float f; uint32 i;} x, y; x.f = a; y.f = b;
  uint32 lo = ((x.i + 0x7fffu + ((x.i >> 16) & 1u)) >> 16);
  uint32 hi = ((y.i + 0x7fffu + ((y.i >> 16) & 1u)) & 0xffff0000u);
  return lo | hi;
}
__device__ __forceinline__ void unp8(uint4 v, float* f){
  union {uint32 i; float x;} a;
  a.i = v.x << 16;         f[0] = a.x;
  a.i = v.x & 0xffff0000u; f[1] = a.x;
  a.i = v.y << 16;         f[2] = a.x;
  a.i = v.y & 0xffff0000u; f[3] = a.x;
  a.i = v.z << 16;         f[4] = a.x;
  a.i = v.z & 0xffff0000u; f[5] = a.x;
  a.i = v.w << 16;         f[6] = a.x;
  a.i = v.w & 0xffff0000u; f[7] = a.x;
}

// ---------------------------------------------------------------------------
// K0: qk_w'[e,d] = 0.125 * sum_j q[e,j]*kp_w[e*64+j, d]; qk_b'[e] similarly.
// grid 16 (e*2 + half), block 256. All f32 — exact fold.
// ---------------------------------------------------------------------------
__global__ __launch_bounds__(256) void k0_qk(const float* __restrict__ pq,
    const float* __restrict__ kpw, const float* __restrict__ kpb,
    float* __restrict__ qkw, float* __restrict__ qkb){
  int e = blockIdx.x >> 1;
  int d = ((blockIdx.x & 1) << 8) + threadIdx.x;
  float acc = 0.f;
  #pragma unroll 8
  for (int j = 0; j < 64; j++){
    int row = e * 64 + j;
    acc += pq[row] * kpw[(size_t)row * 512 + d];
  }
  qkw[e * 512 + d] = acc * 0.125f;
  if (blockIdx.x == 0 && threadIdx.x < 8){
    int ee = threadIdx.x;
    float a = 0.f;
    for (int j = 0; j < 64; j++) a += pq[ee*64 + j] * kpb[ee*64 + j];
    qkb[ee] = a * 0.125f;
  }
}

// ---------------------------------------------------------------------------
// K1: per-n (n = b*512 + w) block. x = swin[b,:,w,:] + pe[:,w,:] staged in LDS.
//  - memory_k[n,d]  = sum_h x[h,d]*k_w[d,h] + k_b[d]           -> d_out (f32)
//  - scores[e,h]    = x[h,:]·qk_w'[e,:] + qk_b'[e]; softmax_h
//  - y[n,e,d]       = sum_h attn[e,h]*x[h,d]                    -> ws (bf16)
// ---------------------------------------------------------------------------
#define XLD 516   // 512 + 4 pad
__global__ __launch_bounds__(256) void k1_main(const float* __restrict__ swin,
    const float* __restrict__ pe, const float* __restrict__ kw, const float* __restrict__ kb,
    const float* __restrict__ qkw, const float* __restrict__ qkb,
    float* __restrict__ outk, u16* __restrict__ y){
  __shared__ float xs[16 * XLD];
  __shared__ float sc[128];
  __shared__ float at[128];
  const int tid = threadIdx.x;
  const int n = blockIdx.x;
  const int b = n >> 9, w = n & 511;

  // ---- load x = swin + pe (float4 loads; rows are [h][d], d contiguous) ----
  {
    const float4* s4 = (const float4*)swin;   // h-row stride = 512*512/4 = 65536 float4
    const float4* p4 = (const float4*)pe;
    const size_t sbase = (size_t)b * 16 * 65536 + (size_t)w * 128;
    const size_t pbase = (size_t)w * 128;
    #pragma unroll
    for (int i = 0; i < 8; i++){
      int f = i * 256 + tid;
      int h = f >> 7, c4 = f & 127;
      float4 av = s4[sbase + (size_t)h * 65536 + c4];
      float4 pv = p4[pbase + (size_t)h * 65536 + c4];
      float* dst = &xs[h * XLD + c4 * 4];
      dst[0] = av.x + pv.x; dst[1] = av.y + pv.y;
      dst[2] = av.z + pv.z; dst[3] = av.w + pv.w;
    }
  }
  __syncthreads();

  // ---- memory_k ----
  #pragma unroll
  for (int r = 0; r < 2; r++){
    int d = (r << 8) + tid;
    const float4* kr = (const float4*)kw + d * 4;   // k_w row d: 16 f32 = 4x float4
    float kf[16];
    *(float4*)&kf[0]  = kr[0]; *(float4*)&kf[4]  = kr[1];
    *(float4*)&kf[8]  = kr[2]; *(float4*)&kf[12] = kr[3];
    float acc = kb[d];
    #pragma unroll
    for (int h = 0; h < 16; h++) acc += xs[h * XLD + d] * kf[h];
    outk[(size_t)n * 512 + d] = acc;
  }

  // ---- scores: pair of lanes per (e,h), each sums 256 d ----
  {
    int p = tid >> 1, half = tid & 1;
    int e = p >> 4, h = p & 15;
    const float*  xr = &xs[h * XLD + (half << 8)];
    const float4* qr = (const float4*)&qkw[e * 512 + (half << 8)];
    float acc = 0.f;
    #pragma unroll 8
    for (int i = 0; i < 64; i++){
      float4 xv = *(const float4*)&xr[i * 4];
      float4 qv = qr[i];
      acc += xv.x*qv.x + xv.y*qv.y + xv.z*qv.z + xv.w*qv.w;
    }
    acc += __shfl_xor(acc, 1);
    if (!half) sc[p] = acc + qkb[e];
  }
  __syncthreads();

  // ---- softmax over h (16 bins), one lane per head ----
  if (tid < 8){
    float m = -1e30f;
    #pragma unroll
    for (int h = 0; h < 16; h++) m = fmaxf(m, sc[tid*16 + h]);
    float ex[16]; float s = 0.f;
    #pragma unroll
    for (int h = 0; h < 16; h++){ ex[h] = __expf(sc[tid*16 + h] - m); s += ex[h]; }
    float inv = 1.f / s;
    #pragma unroll
    for (int h = 0; h < 16; h++) at[tid*16 + h] = ex[h] * inv;
  }
  __syncthreads();

  // ---- y[e,d] = sum_h attn[e,h]*x[h,d]; wave wv owns e0=2wv,e0+1 ----
  {
    int wv = tid >> 6, lane = tid & 63;
    int e0 = wv << 1;
    float ar0[16], ar1[16];
    #pragma unroll
    for (int h = 0; h < 16; h++){ ar0[h] = at[e0*16 + h]; ar1[h] = at[e0*16 + 16 + h]; }
    int da = lane << 2, db = 256 + (lane << 2);
    float a00[4] = {0,0,0,0}, a01[4] = {0,0,0,0}, a10[4] = {0,0,0,0}, a11[4] = {0,0,0,0};
    #pragma unroll
    for (int h = 0; h < 16; h++){
      float4 x0 = *(const float4*)&xs[h * XLD + da];
      float4 x1 = *(const float4*)&xs[h * XLD + db];
      float c0 = ar0[h], c1 = ar1[h];
      a00[0] += c0*x0.x; a00[1] += c0*x0.y; a00[2] += c0*x0.z; a00[3] += c0*x0.w;
      a01[0] += c0*x1.x; a01[1] += c0*x1.y; a01[2] += c0*x1.z; a01[3] += c0*x1.w;
      a10[0] += c1*x0.x; a10[1] += c1*x0.y; a10[2] += c1*x0.z; a10[3] += c1*x0.w;
      a11[0] += c1*x1.x; a11[1] += c1*x1.y; a11[2] += c1*x1.z; a11[3] += c1*x1.w;
    }
    size_t ybase = (size_t)n * 4096;
    uint2 s0;
    s0.x = pk2(a00[0], a00[1]); s0.y = pk2(a00[2], a00[3]);
    *(uint2*)&y[ybase + (size_t)e0 * 512 + da] = s0;
    s0.x = pk2(a01[0], a01[1]); s0.y = pk2(a01[2], a01[3]);
    *(uint2*)&y[ybase + (size_t)e0 * 512 + db] = s0;
    s0.x = pk2(a10[0], a10[1]); s0.y = pk2(a10[2], a10[3]);
    *(uint2*)&y[ybase + (size_t)(e0+1) * 512 + da] = s0;
    s0.x = pk2(a11[0], a11[1]); s0.y = pk2(a11[2], a11[3]);
    *(uint2*)&y[ybase + (size_t)(e0+1) * 512 + db] = s0;
  }
}

// ---------------------------------------------------------------------------
// K2: per 8-n tile. pitch_out[nn,dout] = y[nn,e,:]·vp_w[dout,:] + vp_b[dout],
// then LayerNorm over dout. grid 512, block 512.
// ---------------------------------------------------------------------------
__global__ __launch_bounds__(512) void k2_v(const u16* __restrict__ y,
    const float* __restrict__ vpw, const float* __restrict__ vpb,
    const float* __restrict__ lng, const float* __restrict__ lnb,
    float* __restrict__ outv){
  __shared__ u16 ys[8 * 4096];   // 64 KB bf16 y tile; reused as float ps[8*512] after
  const int tid = threadIdx.x;
  const size_t n0 = (size_t)blockIdx.x * 8;

  {
    const uint4* src = (const uint4*)(y + n0 * 4096);
    uint4* dst = (uint4*)ys;
    #pragma unroll
    for (int i = 0; i < 8; i++) dst[i * 512 + tid] = src[i * 512 + tid];
  }
  __syncthreads();

  const int dout = tid;
  const int e = dout >> 6;                       // wave-uniform -> LDS broadcast reads
  float acc[8];
  float bias = vpb[dout];
  #pragma unroll
  for (int nn = 0; nn < 8; nn++) acc[nn] = bias;

  const float4* vr = (const float4*)vpw + dout * 128;   // own f32 row (L2-hot, 1 MB)
  const uint4*  yb = (const uint4*)ys + (e << 6);
  for (int d8 = 0; d8 < 64; d8++){
    float wf[8];
    *(float4*)&wf[0] = vr[d8 * 2];
    *(float4*)&wf[4] = vr[d8 * 2 + 1];
    #pragma unroll
    for (int nn = 0; nn < 8; nn++){
      float yf[8];
      unp8(yb[nn * 512 + d8], yf);
      acc[nn] += yf[0]*wf[0] + yf[1]*wf[1] + yf[2]*wf[2] + yf[3]*wf[3]
               + yf[4]*wf[4] + yf[5]*wf[5] + yf[6]*wf[6] + yf[7]*wf[7];
    }
  }
  __syncthreads();   // all ys reads done before reuse as f32 scratch

  float* ps = (float*)ys;
  #pragma unroll
  for (int nn = 0; nn < 8; nn++) ps[nn * 512 + dout] = acc[nn];
  __syncthreads();

  {
    int wv = tid >> 6, lane = tid & 63;   // wave wv normalizes row nn = wv
    float vals[8]; float s1 = 0.f, s2 = 0.f;
    #pragma unroll
    for (int j = 0; j < 8; j++){
      float v = ps[wv * 512 + lane + (j << 6)];
      vals[j] = v; s1 += v; s2 += v * v;
    }
    #pragma unroll
    for (int o = 1; o < 64; o <<= 1){ s1 += __shfl_xor(s1, o); s2 += __shfl_xor(s2, o); }
    float mu  = s1 * (1.f / 512.f);
    float var = s2 * (1.f / 512.f) - mu * mu;
    float inv = 1.f / sqrtf(var + 1e-5f);
    float* dst = outv + 2097152 + ((size_t)n0 + wv) * 512;
    #pragma unroll
    for (int j = 0; j < 8; j++){
      int d = lane + (j << 6);
      dst[d] = (vals[j] - mu) * inv * lng[d] + lnb[d];
    }
  }
}

// ---------------------------------------------------------------------------
extern "C" void kernel_launch(void* const* d_in, const int* in_sizes, int n_in,
                              void* d_out, int out_size, void* d_ws, size_t ws_size,
                              hipStream_t stream) {
  const float* swin = (const float*)d_in[0];
  const float* pe   = (const float*)d_in[1];
  const float* pq   = (const float*)d_in[2];
  const float* kw   = (const float*)d_in[3];
  const float* kb   = (const float*)d_in[4];
  const float* kpw  = (const float*)d_in[5];
  const float* kpb  = (const float*)d_in[6];
  const float* vpw  = (const float*)d_in[7];
  const float* vpb  = (const float*)d_in[8];
  const float* lng  = (const float*)d_in[9];
  const float* lnb  = (const float*)d_in[10];
  float* out = (float*)d_out;

  float* qkw = (float*)d_ws;                       // 4096 f32
  float* qkb = qkw + 4096;                         // 8 f32
  u16*   y   = (u16*)((char*)d_ws + 32768);        // 4096 x 4096 bf16 = 32 MB

  k0_qk  <<<16,   256, 0, stream>>>(pq, kpw, kpb, qkw, qkb);
  k1_main<<<4096, 256, 0, stream>>>(swin, pe, kw, kb, qkw, qkb, out, y);
  k2_v   <<<512,  512, 0, stream>>>(y, vpw, vpb, lng, lnb, out);
}

// Round 5
// 291.964 us; speedup vs baseline: 1.1922x; 1.1922x over previous
//
#include <hip/hip_runtime.h>

typedef unsigned int  uint32;
typedef unsigned short u16;
typedef __attribute__((ext_vector_type(8))) short short8x;
typedef __attribute__((ext_vector_type(4))) float f32x4;

// ---------- bf16 helpers ----------
__device__ __forceinline__ float bf2f(u16 u){
  union {uint32 i; float f;} v; v.i = ((uint32)u) << 16; return v.f;
}
__device__ __forceinline__ uint32 pk2(float a, float b){
  union {float f; uint32 i;} x, y; x.f = a; y.f = b;
  uint32 lo = ((x.i + 0x7fffu + ((x.i >> 16) & 1u)) >> 16);
  uint32 hi = ((y.i + 0x7fffu + ((y.i >> 16) & 1u)) & 0xffff0000u);
  return lo | hi;
}
__device__ __forceinline__ void unp8(uint4 v, float* f){
  union {uint32 i; float x;} a;
  a.i = v.x << 16;         f[0] = a.x;
  a.i = v.x & 0xffff0000u; f[1] = a.x;
  a.i = v.y << 16;         f[2] = a.x;
  a.i = v.y & 0xffff0000u; f[3] = a.x;
  a.i = v.z << 16;         f[4] = a.x;
  a.i = v.z & 0xffff0000u; f[5] = a.x;
  a.i = v.w << 16;         f[6] = a.x;
  a.i = v.w & 0xffff0000u; f[7] = a.x;
}

// ---------------------------------------------------------------------------
// K0: qk_w'[e,d] = 0.125 * sum_j q[e,j]*kp_w[e*64+j, d]; qk_b'[e] similarly.
// ---------------------------------------------------------------------------
__global__ __launch_bounds__(256) void k0_qk(const float* __restrict__ pq,
    const float* __restrict__ kpw, const float* __restrict__ kpb,
    float* __restrict__ qkw, float* __restrict__ qkb){
  int e = blockIdx.x >> 1;
  int d = ((blockIdx.x & 1) << 8) + threadIdx.x;
  float acc = 0.f;
  #pragma unroll 8
  for (int j = 0; j < 64; j++){
    int row = e * 64 + j;
    acc += pq[row] * kpw[(size_t)row * 512 + d];
  }
  qkw[e * 512 + d] = acc * 0.125f;
  if (blockIdx.x == 0 && threadIdx.x < 8){
    int ee = threadIdx.x;
    float a = 0.f;
    for (int j = 0; j < 64; j++) a += pq[ee*64 + j] * kpb[ee*64 + j];
    qkb[ee] = a * 0.125f;
  }
}

// ---------------------------------------------------------------------------
// K0b: vp_w f32 -> bf16 (RNE), row-major [512][512]. 128 blocks x 256 thr x 8.
// ---------------------------------------------------------------------------
__global__ __launch_bounds__(256) void k0b_cvt(const float* __restrict__ vpw,
    u16* __restrict__ wb){
  int g = blockIdx.x * 256 + threadIdx.x;          // 32768 groups of 8
  const float4* s = (const float4*)vpw + (size_t)g * 2;
  float4 a = s[0], b = s[1];
  uint4 o;
  o.x = pk2(a.x, a.y); o.y = pk2(a.z, a.w);
  o.z = pk2(b.x, b.y); o.w = pk2(b.z, b.w);
  ((uint4*)wb)[g] = o;
}

// ---------------------------------------------------------------------------
// K1: per-n block. x = swin[b,:,w,:] + pe[:,w,:] staged in LDS as bf16
// (17.7 KB -> 8 blocks/CU vs 4 at f32).
//  - memory_k -> d_out f32;  softmax(scores);  y[n,e,:] -> ws bf16
// ---------------------------------------------------------------------------
#define LDX 520   // bf16 elems/row: stride 1040B = 260 words = 4 mod 32 banks
__global__ __launch_bounds__(256) void k1_main(const float* __restrict__ swin,
    const float* __restrict__ pe, const float* __restrict__ kw, const float* __restrict__ kb,
    const float* __restrict__ qkw, const float* __restrict__ qkb,
    float* __restrict__ outk, u16* __restrict__ y){
  __shared__ u16 xs[16 * LDX];
  __shared__ float sc[128];
  __shared__ float at[128];
  const int tid = threadIdx.x;
  const int n = blockIdx.x;
  const int b = n >> 9, w = n & 511;

  // ---- load x = swin + pe, pack to bf16 LDS ----
  {
    const float4* s4 = (const float4*)swin;   // h-row stride = 65536 float4
    const float4* p4 = (const float4*)pe;
    const size_t sbase = (size_t)b * 16 * 65536 + (size_t)w * 128;
    const size_t pbase = (size_t)w * 128;
    #pragma unroll
    for (int i = 0; i < 4; i++){
      int g = i * 256 + tid;              // 1024 groups of 8 f32
      int h = g >> 6, c8 = g & 63;
      size_t o = (size_t)h * 65536 + c8 * 2;
      float4 a0 = s4[sbase + o],     p0 = p4[pbase + o];
      float4 a1 = s4[sbase + o + 1], p1 = p4[pbase + o + 1];
      uint4 pk;
      pk.x = pk2(a0.x + p0.x, a0.y + p0.y);
      pk.y = pk2(a0.z + p0.z, a0.w + p0.w);
      pk.z = pk2(a1.x + p1.x, a1.y + p1.y);
      pk.w = pk2(a1.z + p1.z, a1.w + p1.w);
      *(uint4*)&xs[h * LDX + c8 * 8] = pk;
    }
  }
  __syncthreads();

  // ---- memory_k ----
  #pragma unroll
  for (int r = 0; r < 2; r++){
    int d = (r << 8) + tid;
    const float4* kr = (const float4*)kw + d * 4;
    float kf[16];
    *(float4*)&kf[0]  = kr[0]; *(float4*)&kf[4]  = kr[1];
    *(float4*)&kf[8]  = kr[2]; *(float4*)&kf[12] = kr[3];
    float acc = kb[d];
    #pragma unroll
    for (int h = 0; h < 16; h++) acc += bf2f(xs[h * LDX + d]) * kf[h];
    outk[(size_t)n * 512 + d] = acc;
  }

  // ---- scores: pair of lanes per (e,h), each sums 256 d (32 x 8 bf16) ----
  {
    int p = tid >> 1, half = tid & 1;
    int e = p >> 4, h = p & 15;
    const uint4*  xr = (const uint4*)&xs[h * LDX + (half << 8)];
    const float4* qr = (const float4*)&qkw[e * 512 + (half << 8)];
    float acc = 0.f;
    #pragma unroll 4
    for (int i = 0; i < 32; i++){
      float xf[8];
      unp8(xr[i], xf);
      float4 q0 = qr[i * 2], q1 = qr[i * 2 + 1];
      acc += xf[0]*q0.x + xf[1]*q0.y + xf[2]*q0.z + xf[3]*q0.w
           + xf[4]*q1.x + xf[5]*q1.y + xf[6]*q1.z + xf[7]*q1.w;
    }
    acc += __shfl_xor(acc, 1);
    if (!half) sc[p] = acc + qkb[e];
  }
  __syncthreads();

  // ---- softmax over h (16 bins), one lane per head ----
  if (tid < 8){
    float m = -1e30f;
    #pragma unroll
    for (int h = 0; h < 16; h++) m = fmaxf(m, sc[tid*16 + h]);
    float ex[16]; float s = 0.f;
    #pragma unroll
    for (int h = 0; h < 16; h++){ ex[h] = __expf(sc[tid*16 + h] - m); s += ex[h]; }
    float inv = 1.f / s;
    #pragma unroll
    for (int h = 0; h < 16; h++) at[tid*16 + h] = ex[h] * inv;
  }
  __syncthreads();

  // ---- y[e,d] = sum_h attn[e,h]*x[h,d]; wave wv owns e0=2wv, e0+1;
  //      lane owns d = lane*8..lane*8+7 (one uint4/h, shared by both e) ----
  {
    int wv = tid >> 6, lane = tid & 63;
    int e0 = wv << 1;
    float ar0[16], ar1[16];
    #pragma unroll
    for (int h = 0; h < 16; h++){ ar0[h] = at[e0*16 + h]; ar1[h] = at[e0*16 + 16 + h]; }
    float a0[8] = {0,0,0,0,0,0,0,0}, a1[8] = {0,0,0,0,0,0,0,0};
    const int da = lane << 3;
    #pragma unroll
    for (int h = 0; h < 16; h++){
      uint4 xv = *(const uint4*)&xs[h * LDX + da];
      float xf[8];
      unp8(xv, xf);
      float c0 = ar0[h], c1 = ar1[h];
      #pragma unroll
      for (int j = 0; j < 8; j++){ a0[j] += c0 * xf[j]; a1[j] += c1 * xf[j]; }
    }
    size_t ybase = (size_t)n * 4096 + da;
    uint4 o;
    o.x = pk2(a0[0],a0[1]); o.y = pk2(a0[2],a0[3]);
    o.z = pk2(a0[4],a0[5]); o.w = pk2(a0[6],a0[7]);
    *(uint4*)&y[ybase + (size_t)e0 * 512] = o;
    o.x = pk2(a1[0],a1[1]); o.y = pk2(a1[2],a1[3]);
    o.z = pk2(a1[4],a1[5]); o.w = pk2(a1[6],a1[7]);
    *(uint4*)&y[ybase + (size_t)(e0+1) * 512] = o;
  }
}

// ---------------------------------------------------------------------------
// K2: 8 independent GEMMs C_e[4096x64] = Y_e[4096x512] @ W_e^T via
// mfma_f32_16x16x32_bf16. Block = (e, 64-row n-tile), 256 thr = 4 waves,
// each wave one 32x32 C-quadrant. BK=128, padded LDS rows (272B stride).
// Writes pitch_out (+bias) f32 to ws.
// ---------------------------------------------------------------------------
#define LDK 136
__global__ __launch_bounds__(256) void k2_gemm(const u16* __restrict__ y,
    const u16* __restrict__ wb, const float* __restrict__ vpb,
    float* __restrict__ pout){
  __shared__ u16 As[64 * LDK];
  __shared__ u16 Bs[64 * LDK];
  const int tid = threadIdx.x;
  const int e = blockIdx.x >> 6, nt = blockIdx.x & 63;
  const int n0 = nt * 64;
  const int wv = tid >> 6, lane = tid & 63;
  const int mrow = (wv >> 1) * 32, ncol = (wv & 1) * 32;
  const int lr = lane & 15, lk = (lane >> 4) * 8;
  f32x4 acc[2][2] = {{{0.f,0.f,0.f,0.f},{0.f,0.f,0.f,0.f}},
                     {{0.f,0.f,0.f,0.f},{0.f,0.f,0.f,0.f}}};
  const int sr = tid >> 2, seg = tid & 3;   // staging: row 0..63, 32-k segment

  for (int kc = 0; kc < 4; kc++){
    const u16* ga = y  + (size_t)(n0 + sr) * 4096 + e * 512 + kc * 128 + seg * 32;
    const u16* gb = wb + (size_t)(e * 64 + sr) * 512 + kc * 128 + seg * 32;
    u16* la = &As[sr * LDK + seg * 32];
    u16* lb = &Bs[sr * LDK + seg * 32];
    #pragma unroll
    for (int u = 0; u < 4; u++){
      *(uint4*)(la + u * 8) = *(const uint4*)(ga + u * 8);
      *(uint4*)(lb + u * 8) = *(const uint4*)(gb + u * 8);
    }
    __syncthreads();
    #pragma unroll
    for (int kk = 0; kk < 4; kk++){
      int kb = kk * 32 + lk;
      short8x af[2], bf[2];
      #pragma unroll
      for (int m = 0; m < 2; m++)
        af[m] = *(const short8x*)&As[(mrow + m * 16 + lr) * LDK + kb];
      #pragma unroll
      for (int nq = 0; nq < 2; nq++)
        bf[nq] = *(const short8x*)&Bs[(ncol + nq * 16 + lr) * LDK + kb];
      #pragma unroll
      for (int m = 0; m < 2; m++)
        #pragma unroll
        for (int nq = 0; nq < 2; nq++)
          acc[m][nq] = __builtin_amdgcn_mfma_f32_16x16x32_bf16(
              af[m], bf[nq], acc[m][nq], 0, 0, 0);
    }
    __syncthreads();
  }
  // epilogue: D row (n-dim) = (lane>>4)*4+j, col (dout-dim) = lane&15
  #pragma unroll
  for (int m = 0; m < 2; m++){
    int gn = n0 + mrow + m * 16 + (lane >> 4) * 4;
    #pragma unroll
    for (int nq = 0; nq < 2; nq++){
      int gd = e * 64 + ncol + nq * 16 + lr;
      float bias = vpb[gd];
      #pragma unroll
      for (int j = 0; j < 4; j++)
        pout[(size_t)(gn + j) * 512 + gd] = acc[m][nq][j] + bias;
    }
  }
}

// ---------------------------------------------------------------------------
// K3: LayerNorm over D=512 per row; 4 rows/block (one per wave).
// ---------------------------------------------------------------------------
__global__ __launch_bounds__(256) void k3_ln(const float* __restrict__ pout,
    const float* __restrict__ lng, const float* __restrict__ lnb,
    float* __restrict__ outv){
  const int row  = blockIdx.x * 4 + (threadIdx.x >> 6);
  const int lane = threadIdx.x & 63;
  const float4* src = (const float4*)(pout + (size_t)row * 512);
  float4 v0 = src[lane * 2], v1 = src[lane * 2 + 1];
  float s1 = v0.x + v0.y + v0.z + v0.w + v1.x + v1.y + v1.z + v1.w;
  float s2 = v0.x*v0.x + v0.y*v0.y + v0.z*v0.z + v0.w*v0.w
           + v1.x*v1.x + v1.y*v1.y + v1.z*v1.z + v1.w*v1.w;
  #pragma unroll
  for (int o = 1; o < 64; o <<= 1){ s1 += __shfl_xor(s1, o); s2 += __shfl_xor(s2, o); }
  float mu  = s1 * (1.f / 512.f);
  float var = s2 * (1.f / 512.f) - mu * mu;
  float inv = 1.f / sqrtf(var + 1e-5f);
  const int d0 = lane * 8;
  const float4* g4 = (const float4*)(lng + d0);
  const float4* b4 = (const float4*)(lnb + d0);
  float4 g0 = g4[0], g1 = g4[1], bb0 = b4[0], bb1 = b4[1];
  float* dst = outv + 2097152 + (size_t)row * 512 + d0;
  float4 o0, o1;
  o0.x = (v0.x - mu) * inv * g0.x + bb0.x;
  o0.y = (v0.y - mu) * inv * g0.y + bb0.y;
  o0.z = (v0.z - mu) * inv * g0.z + bb0.z;
  o0.w = (v0.w - mu) * inv * g0.w + bb0.w;
  o1.x = (v1.x - mu) * inv * g1.x + bb1.x;
  o1.y = (v1.y - mu) * inv * g1.y + bb1.y;
  o1.z = (v1.z - mu) * inv * g1.z + bb1.z;
  o1.w = (v1.w - mu) * inv * g1.w + bb1.w;
  *(float4*)dst       = o0;
  *(float4*)(dst + 4) = o1;
}

// ---------------------------------------------------------------------------
extern "C" void kernel_launch(void* const* d_in, const int* in_sizes, int n_in,
                              void* d_out, int out_size, void* d_ws, size_t ws_size,
                              hipStream_t stream) {
  const float* swin = (const float*)d_in[0];
  const float* pe   = (const float*)d_in[1];
  const float* pq   = (const float*)d_in[2];
  const float* kw   = (const float*)d_in[3];
  const float* kb   = (const float*)d_in[4];
  const float* kpw  = (const float*)d_in[5];
  const float* kpb  = (const float*)d_in[6];
  const float* vpw  = (const float*)d_in[7];
  const float* vpb  = (const float*)d_in[8];
  const float* lng  = (const float*)d_in[9];
  const float* lnb  = (const float*)d_in[10];
  float* out = (float*)d_out;

  // ws layout: [qkw 16KB | qkb | pad to 32KB][y 32MB][wb 512KB][pout 8MB]
  float* qkw  = (float*)d_ws;
  float* qkb  = qkw + 4096;
  u16*   y    = (u16*)((char*)d_ws + 32768);
  u16*   wbuf = (u16*)((char*)d_ws + 32768 + 33554432);
  float* pout = (float*)((char*)d_ws + 32768 + 33554432 + 524288);

  k0_qk  <<<16,   256, 0, stream>>>(pq, kpw, kpb, qkw, qkb);
  k0b_cvt<<<128,  256, 0, stream>>>(vpw, wbuf);
  k1_main<<<4096, 256, 0, stream>>>(swin, pe, kw, kb, qkw, qkb, out, y);
  k2_gemm<<<512,  256, 0, stream>>>(y, wbuf, vpb, pout);
  k3_ln  <<<1024, 256, 0, stream>>>(pout, lng, lnb, out);
}